// Round 7
// baseline (228.409 us; speedup 1.0000x reference)
//
#include <hip/hip_runtime.h>
#include <stdint.h>

#define N_PTS 1000000
#define B_SEG 64
#define HID 128
#define AFFD 16
#define AH 64
#define AL 32
#define AA 8

#define TPB 256                 // 4 waves per block
#define NT 8                    // 16-point tiles per wave (R7: was 16)
#define PTS_WAVE (16 * NT)      // 128
#define PTS_BLK (PTS_WAVE * 4)  // 512
#define MAX_REP 8               // ws replication to kill atomic hot-spot

// Output flat offsets in FLOAT elements (return order: affordances, recon_pos,
// coh_signal, coh_spatial, agent_action, agent_h_next). Output dtype: float32.
#define O_AFF 0
#define O_REC (16 * N_PTS)
#define O_SIG (19 * N_PTS)
#define O_SPA (19 * N_PTS + B_SEG)
#define O_ACT (20 * N_PTS + B_SEG)
#define O_HN  (20 * N_PTS + B_SEG + B_SEG * AA)

// ---------------------------------------------------------------------------
// R7: latency-bound fix on top of R6's MFMA port (R6: 107us, MfmaUtil 8.7,
// VALUBusy 30, Occ 17.5 => avg wave lifetime ~39us = ~5900cyc/tile vs ~1000
// cyc dep-chain => nothing saturated, chain bubbles unhidden at 1.4 w/SIMD).
//   (1) NT 16->8: grid 977->1954 blocks (7.6 blocks/CU supply).
//   (2) 2-tile ILP: two independent tiles interleave their MFMA/cvt chains;
//       F2/G2 K-accumulation split into 2 partial chains (dep 4->2).
//   (3) ws replicated x8 by blockIdx%rep (agent sums replicas): removes the
//       wave-end atomic funnel into one 4.6KB region (sorted batch => blocks
//       co-scheduled on same segment lines).
//   (4) per-wave sortedness check (batch[first]==batch[last]) replaces
//       per-tile __shfl/__all in the hot path.
// Transposed MFMA layout (R6-verified on HW): each layer's C-frag
// (col=pt=lane&15, row=4q+reg) is lane-identical to next layer's B-frag
// (n=pt=lane&15, k=4q+(e&3)+16(e>>2)). Biases in spare K lanes.
// ws layout: [rep][seg][18] = {err_sum, count, aff_sum[16]} (fp32)
// ---------------------------------------------------------------------------

typedef __attribute__((ext_vector_type(8))) short bf16x8;  // 8 bf16, 4 VGPRs
typedef __attribute__((ext_vector_type(4))) float f32x4;   // C/D frag

static __device__ __forceinline__ short f2bf(float f) {
  __bf16 b = (__bf16)f;  // hardware cvt, RNE
  return __builtin_bit_cast(short, b);
}

__global__ __launch_bounds__(TPB, 1) void point_kernel(
    const float* __restrict__ pos, const int* __restrict__ batch,
    const float* __restrict__ Wf1, const float* __restrict__ bf1v,
    const float* __restrict__ Wf2, const float* __restrict__ bf2v,
    const float* __restrict__ Wg1, const float* __restrict__ bg1v,
    const float* __restrict__ Wg2, const float* __restrict__ bg2v,
    float* __restrict__ out, float* __restrict__ ws, int rep) {
  const int lane = threadIdx.x & 63;
  const int wid = threadIdx.x >> 6;
  const int m = lane & 15;  // point-in-tile (N) / output row (M) index
  const int q = lane >> 4;  // k-quartet group
  const int wbase = blockIdx.x * PTS_BLK + wid * PTS_WAVE;
  float* __restrict__ wsr = ws + (size_t)(blockIdx.x % rep) * (B_SEG * 18);

  // ---- preload all weight A-fragments (once per wave) ----
  // A-frag element e of lane (m,q) holds A[row=m][k = 4q + (e&3) + 16*(e>>2)].
  bf16x8 Af1[8], Ag1[8], Af2[4], Ag2[4];
#pragma unroll
  for (int jb = 0; jb < 8; jb++) {
    const int j = jb * 16 + m;
    bf16x8 a = {0, 0, 0, 0, 0, 0, 0, 0};
    if (q == 0) {
      a[0] = f2bf(Wf1[0 * HID + j]);
      a[1] = f2bf(Wf1[1 * HID + j]);
      a[2] = f2bf(Wf1[2 * HID + j]);
      a[3] = f2bf(bf1v[j]);
    }
    Af1[jb] = a;
    bf16x8 g = {0, 0, 0, 0, 0, 0, 0, 0};
#pragma unroll
    for (int e = 0; e < 4; e++) g[e] = f2bf(Wg1[(4 * q + e) * HID + j]);
    if (q == 0) g[4] = f2bf(bg1v[j]);
    Ag1[jb] = g;
  }
#pragma unroll
  for (int kb = 0; kb < 4; kb++) {
    bf16x8 a2, g2;
#pragma unroll
    for (int e = 0; e < 8; e++) {
      const int j = kb * 32 + 4 * q + (e & 3) + 16 * (e >> 2);
      a2[e] = f2bf(Wf2[j * AFFD + m]);                       // A = Wf2^T (a x j)
      g2[e] = (m < 3) ? f2bf(Wg2[j * 3 + m]) : (short)0;    // A = Wg2^T (r x j)
    }
    Af2[kb] = a2;
    Ag2[kb] = g2;
  }
  const float bf2r0 = bf2v[4 * q + 0], bf2r1 = bf2v[4 * q + 1];
  const float bf2r2 = bf2v[4 * q + 2], bf2r3 = bf2v[4 * q + 3];
  const float bg20 = bg2v[0], bg21 = bg2v[1], bg22 = bg2v[2];
  const short one = (short)0x3F80;  // 1.0 in bf16
  const f32x4 zf = {0.f, 0.f, 0.f, 0.f};

  // segment accumulator (register, flushed on seg change / wave end)
  int cur = -1, cntT = 0;
  float acc0 = 0.f, acc1 = 0.f, acc2 = 0.f, acc3 = 0.f, accE = 0.f;

  auto flush = [&]() {
    float r0 = acc0, r1 = acc1, r2 = acc2, r3 = acc3, re = accE;
#pragma unroll
    for (int msk = 1; msk <= 8; msk <<= 1) {
      r0 += __shfl_xor(r0, msk);
      r1 += __shfl_xor(r1, msk);
      r2 += __shfl_xor(r2, msk);
      r3 += __shfl_xor(r3, msk);
      re += __shfl_xor(re, msk);
    }
    if (m == 0) {
      float* wp = wsr + cur * 18;
      atomicAdd(wp + 2 + 4 * q + 0, r0);
      atomicAdd(wp + 2 + 4 * q + 1, r1);
      atomicAdd(wp + 2 + 4 * q + 2, r2);
      atomicAdd(wp + 2 + 4 * q + 3, r3);
      if (q == 0) {
        atomicAdd(wp + 0, re);
        atomicAdd(wp + 1, 16.f * (float)cntT);
      }
    }
    acc0 = acc1 = acc2 = acc3 = accE = 0.f;
    cntT = 0;
  };

  // Compute a PAIR of independent 16-point tiles (2x ILP on the MFMA chain),
  // do the global stores, return per-lane aff quads / errors / segs / valid.
  auto do_pair = [&](int pt0, float (&aa)[2][4], float (&ee)[2], int (&sgv)[2],
                     bool (&vv)[2]) {
    float X[2], Y[2], Z[2];
    bf16x8 Bp[2];
#pragma unroll
    for (int u = 0; u < 2; u++) {
      const int p = pt0 + 16 * u + m;
      vv[u] = (p < N_PTS);
      const int pc = vv[u] ? p : (N_PTS - 1);
      X[u] = pos[pc * 3 + 0];
      Y[u] = pos[pc * 3 + 1];
      Z[u] = pos[pc * 3 + 2];
      sgv[u] = batch[pc];
      bf16x8 b = {0, 0, 0, 0, 0, 0, 0, 0};
      if (q == 0) {
        b[0] = f2bf(X[u]);
        b[1] = f2bf(Y[u]);
        b[2] = f2bf(Z[u]);
        b[3] = one;
      }
      Bp[u] = b;
    }

    // F1 (8 independent MFMAs per tile) + in-lane relu/cvt.
    bf16x8 Bh[2][4];
#pragma unroll
    for (int u = 0; u < 2; u++)
#pragma unroll
      for (int kb = 0; kb < 4; kb++) {
        f32x4 c0 = __builtin_amdgcn_mfma_f32_16x16x32_bf16(Af1[2 * kb + 0], Bp[u], zf, 0, 0, 0);
        f32x4 c1 = __builtin_amdgcn_mfma_f32_16x16x32_bf16(Af1[2 * kb + 1], Bp[u], zf, 0, 0, 0);
        bf16x8 b;
        b[0] = f2bf(fmaxf(c0[0], 0.f));
        b[1] = f2bf(fmaxf(c0[1], 0.f));
        b[2] = f2bf(fmaxf(c0[2], 0.f));
        b[3] = f2bf(fmaxf(c0[3], 0.f));
        b[4] = f2bf(fmaxf(c1[0], 0.f));
        b[5] = f2bf(fmaxf(c1[1], 0.f));
        b[6] = f2bf(fmaxf(c1[2], 0.f));
        b[7] = f2bf(fmaxf(c1[3], 0.f));
        Bh[u][kb] = b;
      }

    // F2: split K-chain (dep depth 2) per tile.
    bf16x8 Ba[2];
#pragma unroll
    for (int u = 0; u < 2; u++) {
      f32x4 c01 = __builtin_amdgcn_mfma_f32_16x16x32_bf16(Af2[0], Bh[u][0], zf, 0, 0, 0);
      c01 = __builtin_amdgcn_mfma_f32_16x16x32_bf16(Af2[1], Bh[u][1], c01, 0, 0, 0);
      f32x4 c23 = __builtin_amdgcn_mfma_f32_16x16x32_bf16(Af2[2], Bh[u][2], zf, 0, 0, 0);
      c23 = __builtin_amdgcn_mfma_f32_16x16x32_bf16(Af2[3], Bh[u][3], c23, 0, 0, 0);
      aa[u][0] = c01[0] + c23[0] + bf2r0;
      aa[u][1] = c01[1] + c23[1] + bf2r1;
      aa[u][2] = c01[2] + c23[2] + bf2r2;
      aa[u][3] = c01[3] + c23[3] + bf2r3;
      bf16x8 b;
      b[0] = f2bf(aa[u][0]);
      b[1] = f2bf(aa[u][1]);
      b[2] = f2bf(aa[u][2]);
      b[3] = f2bf(aa[u][3]);
      b[4] = one;  // bias row k=16 (q>0 lanes hit zero A rows: harmless)
      b[5] = 0;
      b[6] = 0;
      b[7] = 0;
      Ba[u] = b;
    }

    // G1 + relu/cvt.
    bf16x8 Bh2[2][4];
#pragma unroll
    for (int u = 0; u < 2; u++)
#pragma unroll
      for (int kb = 0; kb < 4; kb++) {
        f32x4 c0 = __builtin_amdgcn_mfma_f32_16x16x32_bf16(Ag1[2 * kb + 0], Ba[u], zf, 0, 0, 0);
        f32x4 c1 = __builtin_amdgcn_mfma_f32_16x16x32_bf16(Ag1[2 * kb + 1], Ba[u], zf, 0, 0, 0);
        bf16x8 b;
        b[0] = f2bf(fmaxf(c0[0], 0.f));
        b[1] = f2bf(fmaxf(c0[1], 0.f));
        b[2] = f2bf(fmaxf(c0[2], 0.f));
        b[3] = f2bf(fmaxf(c0[3], 0.f));
        b[4] = f2bf(fmaxf(c1[0], 0.f));
        b[5] = f2bf(fmaxf(c1[1], 0.f));
        b[6] = f2bf(fmaxf(c1[2], 0.f));
        b[7] = f2bf(fmaxf(c1[3], 0.f));
        Bh2[u][kb] = b;
      }

#pragma unroll
    for (int u = 0; u < 2; u++) {
      // G2: split K-chain.
      f32x4 c01 = __builtin_amdgcn_mfma_f32_16x16x32_bf16(Ag2[0], Bh2[u][0], zf, 0, 0, 0);
      c01 = __builtin_amdgcn_mfma_f32_16x16x32_bf16(Ag2[1], Bh2[u][1], c01, 0, 0, 0);
      f32x4 c23 = __builtin_amdgcn_mfma_f32_16x16x32_bf16(Ag2[2], Bh2[u][2], zf, 0, 0, 0);
      c23 = __builtin_amdgcn_mfma_f32_16x16x32_bf16(Ag2[3], Bh2[u][3], c23, 0, 0, 0);

      float err = 0.f, rc0 = 0.f, rc1 = 0.f, rc2 = 0.f;
      if (q == 0) {
        rc0 = c01[0] + c23[0] + bg20;
        rc1 = c01[1] + c23[1] + bg21;
        rc2 = c01[2] + c23[2] + bg22;
        const float dx = X[u] - rc0, dy = Y[u] - rc1, dz = Z[u] - rc2;
        err = fmaf(dx, dx, fmaf(dy, dy, dz * dz));
      }
      ee[u] = err;

      if (vv[u]) {
        const int p = pt0 + 16 * u + m;
        float4 st;
        st.x = aa[u][0]; st.y = aa[u][1]; st.z = aa[u][2]; st.w = aa[u][3];
        *(float4*)(out + O_AFF + (size_t)p * 16 + 4 * q) = st;
        if (q == 0) {
          float* orc = out + O_REC + (size_t)p * 3;
          orc[0] = rc0; orc[1] = rc1; orc[2] = rc2;
          out[O_SPA + p] = err;
        }
      }
    }
  };

  // Per-wave sortedness check: batch sorted => first==last means whole wave
  // is one segment (and fully in-bounds).
  const int cA = (wbase < N_PTS) ? wbase : (N_PTS - 1);
  const int cB = (wbase + PTS_WAVE - 1 < N_PTS) ? (wbase + PTS_WAVE - 1) : (N_PTS - 1);
  const int segFirst = batch[cA];
  const bool wave_clean = (wbase + PTS_WAVE <= N_PTS) && (segFirst == batch[cB]);

  float aa[2][4];
  float ee[2];
  int sgv[2];
  bool vv[2];

  if (wave_clean) {
    // Hot path: no per-tile cross-lane logic at all.
#pragma unroll 1
    for (int tt = 0; tt < NT; tt += 2) {
      do_pair(wbase + tt * 16, aa, ee, sgv, vv);
      acc0 += aa[0][0] + aa[1][0];
      acc1 += aa[0][1] + aa[1][1];
      acc2 += aa[0][2] + aa[1][2];
      acc3 += aa[0][3] + aa[1][3];
      accE += ee[0] + ee[1];
    }
    cur = segFirst;
    cntT = NT;
    flush();
  } else {
#pragma unroll 1
    for (int tt = 0; tt < NT; tt += 2) {
      do_pair(wbase + tt * 16, aa, ee, sgv, vv);
#pragma unroll
      for (int u = 0; u < 2; u++) {
        const int pt0u = wbase + (tt + u) * 16;
        const int useg = __shfl(sgv[u], 0);
        const bool cln = __all(sgv[u] == useg) && (pt0u + 16 <= N_PTS);
        if (cln && useg == cur) {
          acc0 += aa[u][0]; acc1 += aa[u][1];
          acc2 += aa[u][2]; acc3 += aa[u][3];
          accE += ee[u];
          cntT++;
        } else {
          if (cntT > 0) flush();
          if (cln) {
            cur = useg;
            acc0 = aa[u][0]; acc1 = aa[u][1];
            acc2 = aa[u][2]; acc3 = aa[u][3];
            accE = ee[u];
            cntT = 1;
          } else {
            cur = -1;
            if (vv[u]) {
              float* wp = wsr + sgv[u] * 18;
              atomicAdd(wp + 2 + 4 * q + 0, aa[u][0]);
              atomicAdd(wp + 2 + 4 * q + 1, aa[u][1]);
              atomicAdd(wp + 2 + 4 * q + 2, aa[u][2]);
              atomicAdd(wp + 2 + 4 * q + 3, aa[u][3]);
              if (q == 0) {
                atomicAdd(wp + 0, ee[u]);
                atomicAdd(wp + 1, 1.f);
              }
            }
          }
        }
      }
    }
    if (cntT > 0) flush();
  }
}

// ---------------------------------------------------------------------------
// Kernel 2: one block per segment (64 blocks x 64 threads). Sums ws replicas.
// ---------------------------------------------------------------------------
__global__ __launch_bounds__(64) void agent_kernel(
    const float* __restrict__ ws, int rep, const float* __restrict__ agent_h,
    const float* __restrict__ Wx, const float* __restrict__ Wh,
    const float* __restrict__ bx, const float* __restrict__ bh,
    const float* __restrict__ Wlat, const float* __restrict__ blat,
    const float* __restrict__ Wact, const float* __restrict__ bact,
    float* __restrict__ out) {
  const int b = blockIdx.x;   // segment
  const int t = threadIdx.x;  // 0..63
  __shared__ float sAff[AFFD];
  __shared__ float sHn[AH];
  __shared__ float sLat[AL];

  float errs = 0.f, cnts = 0.f, affs = 0.f;
  for (int r = 0; r < rep; r++) {
    const float* wp = ws + ((size_t)r * B_SEG + b) * 18;
    errs += wp[0];
    cnts += wp[1];
    if (t < AFFD) affs += wp[2 + t];
  }
  const float cnt = fmaxf(cnts, 1.f);
  if (t == 0) out[O_SIG + b] = errs / cnt;
  if (t < AFFD) sAff[t] = affs / cnt;
  const float h_prev = agent_h[b * AH + t];
  __syncthreads();

  float pr  = bx[t] + bh[t];
  float pz  = bx[64 + t] + bh[64 + t];
  float pnx = bx[128 + t];
  float pnh = bh[128 + t];
#pragma unroll
  for (int k = 0; k < AFFD; k++) {
    const float a = sAff[k];
    pr  = fmaf(a, Wx[k * 192 + t], pr);
    pz  = fmaf(a, Wx[k * 192 + 64 + t], pz);
    pnx = fmaf(a, Wx[k * 192 + 128 + t], pnx);
  }
#pragma unroll
  for (int k = 0; k < AH; k++) {
    const float h = __shfl(h_prev, k);
    pr  = fmaf(h, Wh[k * 192 + t], pr);
    pz  = fmaf(h, Wh[k * 192 + 64 + t], pz);
    pnh = fmaf(h, Wh[k * 192 + 128 + t], pnh);
  }
  const float r = 1.f / (1.f + expf(-pr));
  const float z = 1.f / (1.f + expf(-pz));
  const float n = tanhf(pnx + r * pnh);
  const float hn = fmaf(1.f - z, n, z * h_prev);
  sHn[t] = hn;
  out[O_HN + b * AH + t] = hn;
  __syncthreads();

  if (t < AL) {
    float acc = blat[t];
#pragma unroll
    for (int k = 0; k < AH; k++) acc = fmaf(sHn[k], Wlat[k * AL + t], acc);
    sLat[t] = tanhf(acc);
  }
  __syncthreads();

  if (t < AA) {
    float acc = bact[t];
#pragma unroll
    for (int k = 0; k < AL; k++) acc = fmaf(sLat[k], Wact[k * AA + t], acc);
    out[O_ACT + b * AA + t] = acc;
  }
}

extern "C" void kernel_launch(void* const* d_in, const int* in_sizes, int n_in,
                              void* d_out, int out_size, void* d_ws, size_t ws_size,
                              hipStream_t stream) {
  const float* pos     = (const float*)d_in[0];
  const int*   batch   = (const int*)d_in[1];
  const float* agent_h = (const float*)d_in[2];
  // d_in[3], d_in[4]: coherence_*_prev — unused by the math.
  const float* Wf1  = (const float*)d_in[5];
  const float* bf1v = (const float*)d_in[6];
  const float* Wf2  = (const float*)d_in[7];
  const float* bf2v = (const float*)d_in[8];
  const float* Wg1  = (const float*)d_in[9];
  const float* bg1v = (const float*)d_in[10];
  const float* Wg2  = (const float*)d_in[11];
  const float* bg2v = (const float*)d_in[12];
  const float* Wx   = (const float*)d_in[13];
  const float* Wh   = (const float*)d_in[14];
  const float* bx   = (const float*)d_in[15];
  const float* bh   = (const float*)d_in[16];
  const float* Wlat = (const float*)d_in[17];
  const float* blat = (const float*)d_in[18];
  const float* Wact = (const float*)d_in[19];
  const float* bact = (const float*)d_in[20];
  float* out = (float*)d_out;
  float* ws = (float*)d_ws;

  // ws replicas (atomic de-contention), bounded by the provided workspace.
  const size_t one_rep = (size_t)B_SEG * 18 * sizeof(float);
  int rep = (int)(ws_size / one_rep);
  if (rep > MAX_REP) rep = MAX_REP;
  if (rep < 1) rep = 1;

  // ws is re-poisoned 0xAA before every launch — zero the accumulators.
  hipMemsetAsync(ws, 0, (size_t)rep * one_rep, stream);

  const int nblk = (N_PTS + PTS_BLK - 1) / PTS_BLK;  // 1954
  point_kernel<<<nblk, TPB, 0, stream>>>(pos, batch, Wf1, bf1v, Wf2, bf2v,
                                         Wg1, bg1v, Wg2, bg2v, out, ws, rep);
  agent_kernel<<<B_SEG, 64, 0, stream>>>(ws, rep, agent_h, Wx, Wh, bx, bh,
                                         Wlat, blat, Wact, bact, out);
}

// Round 8
// 210.125 us; speedup vs baseline: 1.0870x; 1.0870x over previous
//
#include <hip/hip_runtime.h>
#include <stdint.h>

#define N_PTS 1000000
#define B_SEG 64
#define HID 128
#define AFFD 16
#define AH 64
#define AL 32
#define AA 8

#define TPB 256                 // 4 waves per block
#define NT 8                    // 16-point tiles per wave
#define PTS_WAVE (16 * NT)      // 128
#define PTS_BLK (PTS_WAVE * 4)  // 512
#define MAX_REP 8               // ws replication to kill atomic hot-spot

// Output flat offsets in FLOAT elements (return order: affordances, recon_pos,
// coh_signal, coh_spatial, agent_action, agent_h_next). Output dtype: float32.
#define O_AFF 0
#define O_REC (16 * N_PTS)
#define O_SIG (19 * N_PTS)
#define O_SPA (19 * N_PTS + B_SEG)
#define O_ACT (20 * N_PTS + B_SEG)
#define O_HN  (20 * N_PTS + B_SEG + B_SEG * AA)

// ---------------------------------------------------------------------------
// R8: software-pipelined clean path on top of R6/R7's MFMA port.
// Evidence: R6 (NT=16, 977 blk) and R7 (NT=8, 1954 blk, 2-tile ILP) are
// IDENTICAL at ~107us: per-wave per-tile time ~5800cyc invariant under grid
// size and ILP; all pipes <35%; dep chain ~600cyc. The ~5000cyc/tile stall
// must be s_waitcnt on VMEM (invisible to busy counters, per-wave serial):
//  (a) pos loads issued at iteration top, consumed immediately -> full
//      L2/HBM latency exposed every iteration;
//  (b) store-data VGPRs reused next iteration -> compiler inserts
//      s_waitcnt vmcnt before overwrite -> store-drain exposed per tile.
// Fix: explicit 2-stage pipeline in the wave_clean path: prefetch pair t+1's
// pos loads BEFORE computing pair t (static buf[pp&1] indexing, rule #20);
// stores at iteration end get a full prefetch+F1 of slack before reuse.
// Clean path also drops batch loads + validity checks (wave_clean proves
// single-segment, in-bounds). Slow path keeps R7's verified code.
// Transposed MFMA layout (R6-verified on HW): each layer's C-frag
// (col=pt=lane&15, row=4q+reg) is lane-identical to next layer's B-frag
// (n=pt=lane&15, k=4q+(e&3)+16(e>>2)). Biases in spare K lanes.
// ws layout: [rep][seg][18] = {err_sum, count, aff_sum[16]} (fp32)
// ---------------------------------------------------------------------------

typedef __attribute__((ext_vector_type(8))) short bf16x8;  // 8 bf16, 4 VGPRs
typedef __attribute__((ext_vector_type(4))) float f32x4;   // C/D frag

static __device__ __forceinline__ short f2bf(float f) {
  __bf16 b = (__bf16)f;  // hardware cvt, RNE
  return __builtin_bit_cast(short, b);
}

__global__ __launch_bounds__(TPB, 2) void point_kernel(
    const float* __restrict__ pos, const int* __restrict__ batch,
    const float* __restrict__ Wf1, const float* __restrict__ bf1v,
    const float* __restrict__ Wf2, const float* __restrict__ bf2v,
    const float* __restrict__ Wg1, const float* __restrict__ bg1v,
    const float* __restrict__ Wg2, const float* __restrict__ bg2v,
    float* __restrict__ out, float* __restrict__ ws, int rep) {
  const int lane = threadIdx.x & 63;
  const int wid = threadIdx.x >> 6;
  const int m = lane & 15;  // point-in-tile (N) / output row (M) index
  const int q = lane >> 4;  // k-quartet group
  const int wbase = blockIdx.x * PTS_BLK + wid * PTS_WAVE;
  float* __restrict__ wsr = ws + (size_t)(blockIdx.x % rep) * (B_SEG * 18);

  // ---- preload all weight A-fragments (once per wave) ----
  // A-frag element e of lane (m,q) holds A[row=m][k = 4q + (e&3) + 16*(e>>2)].
  bf16x8 Af1[8], Ag1[8], Af2[4], Ag2[4];
#pragma unroll
  for (int jb = 0; jb < 8; jb++) {
    const int j = jb * 16 + m;
    bf16x8 a = {0, 0, 0, 0, 0, 0, 0, 0};
    if (q == 0) {
      a[0] = f2bf(Wf1[0 * HID + j]);
      a[1] = f2bf(Wf1[1 * HID + j]);
      a[2] = f2bf(Wf1[2 * HID + j]);
      a[3] = f2bf(bf1v[j]);
    }
    Af1[jb] = a;
    bf16x8 g = {0, 0, 0, 0, 0, 0, 0, 0};
#pragma unroll
    for (int e = 0; e < 4; e++) g[e] = f2bf(Wg1[(4 * q + e) * HID + j]);
    if (q == 0) g[4] = f2bf(bg1v[j]);
    Ag1[jb] = g;
  }
#pragma unroll
  for (int kb = 0; kb < 4; kb++) {
    bf16x8 a2, g2;
#pragma unroll
    for (int e = 0; e < 8; e++) {
      const int j = kb * 32 + 4 * q + (e & 3) + 16 * (e >> 2);
      a2[e] = f2bf(Wf2[j * AFFD + m]);                       // A = Wf2^T (a x j)
      g2[e] = (m < 3) ? f2bf(Wg2[j * 3 + m]) : (short)0;    // A = Wg2^T (r x j)
    }
    Af2[kb] = a2;
    Ag2[kb] = g2;
  }
  const float bf2r0 = bf2v[4 * q + 0], bf2r1 = bf2v[4 * q + 1];
  const float bf2r2 = bf2v[4 * q + 2], bf2r3 = bf2v[4 * q + 3];
  const float bg20 = bg2v[0], bg21 = bg2v[1], bg22 = bg2v[2];
  const short one = (short)0x3F80;  // 1.0 in bf16
  const f32x4 zf = {0.f, 0.f, 0.f, 0.f};

  // segment accumulator (register, flushed on seg change / wave end)
  int cur = -1, cntT = 0;
  float acc0 = 0.f, acc1 = 0.f, acc2 = 0.f, acc3 = 0.f, accE = 0.f;

  auto flush = [&]() {
    float r0 = acc0, r1 = acc1, r2 = acc2, r3 = acc3, re = accE;
#pragma unroll
    for (int msk = 1; msk <= 8; msk <<= 1) {
      r0 += __shfl_xor(r0, msk);
      r1 += __shfl_xor(r1, msk);
      r2 += __shfl_xor(r2, msk);
      r3 += __shfl_xor(r3, msk);
      re += __shfl_xor(re, msk);
    }
    if (m == 0) {
      float* wp = wsr + cur * 18;
      atomicAdd(wp + 2 + 4 * q + 0, r0);
      atomicAdd(wp + 2 + 4 * q + 1, r1);
      atomicAdd(wp + 2 + 4 * q + 2, r2);
      atomicAdd(wp + 2 + 4 * q + 3, r3);
      if (q == 0) {
        atomicAdd(wp + 0, re);
        atomicAdd(wp + 1, 16.f * (float)cntT);
      }
    }
    acc0 = acc1 = acc2 = acc3 = accE = 0.f;
    cntT = 0;
  };

  // Per-wave sortedness check: batch sorted => first==last means whole wave
  // is one segment (and fully in-bounds).
  const int cA = (wbase < N_PTS) ? wbase : (N_PTS - 1);
  const int cB = (wbase + PTS_WAVE - 1 < N_PTS) ? (wbase + PTS_WAVE - 1) : (N_PTS - 1);
  const int segFirst = batch[cA];
  const bool wave_clean = (wbase + PTS_WAVE <= N_PTS) && (segFirst == batch[cB]);

  if (wave_clean) {
    // ---- HOT PATH: 2-stage software pipeline over NT/2 = 4 pairs ----
    float Xb[2][2], Yb[2][2], Zb[2][2];  // [buf][tile-in-pair]
    // prologue: loads for pair 0 into buf 0
#pragma unroll
    for (int u = 0; u < 2; u++) {
      const int p = wbase + 16 * u + m;
      Xb[0][u] = pos[p * 3 + 0];
      Yb[0][u] = pos[p * 3 + 1];
      Zb[0][u] = pos[p * 3 + 2];
    }

#pragma unroll
    for (int pp = 0; pp < NT / 2; pp++) {
      const int cr = pp & 1, nx = cr ^ 1;  // compile-time under full unroll
      // PREFETCH pair pp+1 (issued before any use of pair pp's data beyond
      // what's already loaded; hides L2/HBM latency under the MFMA chain).
      if (pp + 1 < NT / 2) {
#pragma unroll
        for (int u = 0; u < 2; u++) {
          const int p = wbase + (pp + 1) * 32 + 16 * u + m;
          Xb[nx][u] = pos[p * 3 + 0];
          Yb[nx][u] = pos[p * 3 + 1];
          Zb[nx][u] = pos[p * 3 + 2];
        }
      }

      // ---- compute pair pp from buf cr ----
      bf16x8 Bp[2];
#pragma unroll
      for (int u = 0; u < 2; u++) {
        bf16x8 b = {0, 0, 0, 0, 0, 0, 0, 0};
        if (q == 0) {
          b[0] = f2bf(Xb[cr][u]);
          b[1] = f2bf(Yb[cr][u]);
          b[2] = f2bf(Zb[cr][u]);
          b[3] = one;
        }
        Bp[u] = b;
      }

      // F1 + in-lane relu/cvt.
      bf16x8 Bh[2][4];
#pragma unroll
      for (int u = 0; u < 2; u++)
#pragma unroll
        for (int kb = 0; kb < 4; kb++) {
          f32x4 c0 = __builtin_amdgcn_mfma_f32_16x16x32_bf16(Af1[2 * kb + 0], Bp[u], zf, 0, 0, 0);
          f32x4 c1 = __builtin_amdgcn_mfma_f32_16x16x32_bf16(Af1[2 * kb + 1], Bp[u], zf, 0, 0, 0);
          bf16x8 b;
          b[0] = f2bf(fmaxf(c0[0], 0.f));
          b[1] = f2bf(fmaxf(c0[1], 0.f));
          b[2] = f2bf(fmaxf(c0[2], 0.f));
          b[3] = f2bf(fmaxf(c0[3], 0.f));
          b[4] = f2bf(fmaxf(c1[0], 0.f));
          b[5] = f2bf(fmaxf(c1[1], 0.f));
          b[6] = f2bf(fmaxf(c1[2], 0.f));
          b[7] = f2bf(fmaxf(c1[3], 0.f));
          Bh[u][kb] = b;
        }

      // F2 (split K-chain) -> aff.
      float aa[2][4];
      bf16x8 Ba[2];
#pragma unroll
      for (int u = 0; u < 2; u++) {
        f32x4 c01 = __builtin_amdgcn_mfma_f32_16x16x32_bf16(Af2[0], Bh[u][0], zf, 0, 0, 0);
        c01 = __builtin_amdgcn_mfma_f32_16x16x32_bf16(Af2[1], Bh[u][1], c01, 0, 0, 0);
        f32x4 c23 = __builtin_amdgcn_mfma_f32_16x16x32_bf16(Af2[2], Bh[u][2], zf, 0, 0, 0);
        c23 = __builtin_amdgcn_mfma_f32_16x16x32_bf16(Af2[3], Bh[u][3], c23, 0, 0, 0);
        aa[u][0] = c01[0] + c23[0] + bf2r0;
        aa[u][1] = c01[1] + c23[1] + bf2r1;
        aa[u][2] = c01[2] + c23[2] + bf2r2;
        aa[u][3] = c01[3] + c23[3] + bf2r3;
        bf16x8 b;
        b[0] = f2bf(aa[u][0]);
        b[1] = f2bf(aa[u][1]);
        b[2] = f2bf(aa[u][2]);
        b[3] = f2bf(aa[u][3]);
        b[4] = one;  // bias row k=16 (q>0 lanes hit zero A rows: harmless)
        b[5] = 0;
        b[6] = 0;
        b[7] = 0;
        Ba[u] = b;
      }

      // G1 + relu/cvt.
      bf16x8 Bh2[2][4];
#pragma unroll
      for (int u = 0; u < 2; u++)
#pragma unroll
        for (int kb = 0; kb < 4; kb++) {
          f32x4 c0 = __builtin_amdgcn_mfma_f32_16x16x32_bf16(Ag1[2 * kb + 0], Ba[u], zf, 0, 0, 0);
          f32x4 c1 = __builtin_amdgcn_mfma_f32_16x16x32_bf16(Ag1[2 * kb + 1], Ba[u], zf, 0, 0, 0);
          bf16x8 b;
          b[0] = f2bf(fmaxf(c0[0], 0.f));
          b[1] = f2bf(fmaxf(c0[1], 0.f));
          b[2] = f2bf(fmaxf(c0[2], 0.f));
          b[3] = f2bf(fmaxf(c0[3], 0.f));
          b[4] = f2bf(fmaxf(c1[0], 0.f));
          b[5] = f2bf(fmaxf(c1[1], 0.f));
          b[6] = f2bf(fmaxf(c1[2], 0.f));
          b[7] = f2bf(fmaxf(c1[3], 0.f));
          Bh2[u][kb] = b;
        }

      // G2 (split K-chain) -> recon + err; accumulate; stores LAST.
#pragma unroll
      for (int u = 0; u < 2; u++) {
        f32x4 c01 = __builtin_amdgcn_mfma_f32_16x16x32_bf16(Ag2[0], Bh2[u][0], zf, 0, 0, 0);
        c01 = __builtin_amdgcn_mfma_f32_16x16x32_bf16(Ag2[1], Bh2[u][1], c01, 0, 0, 0);
        f32x4 c23 = __builtin_amdgcn_mfma_f32_16x16x32_bf16(Ag2[2], Bh2[u][2], zf, 0, 0, 0);
        c23 = __builtin_amdgcn_mfma_f32_16x16x32_bf16(Ag2[3], Bh2[u][3], c23, 0, 0, 0);

        float err = 0.f, rc0 = 0.f, rc1 = 0.f, rc2 = 0.f;
        if (q == 0) {
          rc0 = c01[0] + c23[0] + bg20;
          rc1 = c01[1] + c23[1] + bg21;
          rc2 = c01[2] + c23[2] + bg22;
          const float dx = Xb[cr][u] - rc0, dy = Yb[cr][u] - rc1, dz = Zb[cr][u] - rc2;
          err = fmaf(dx, dx, fmaf(dy, dy, dz * dz));
        }
        acc0 += aa[u][0];
        acc1 += aa[u][1];
        acc2 += aa[u][2];
        acc3 += aa[u][3];
        accE += err;  // err==0 on q>0

        const int p = wbase + pp * 32 + 16 * u + m;
        float4 st;
        st.x = aa[u][0]; st.y = aa[u][1]; st.z = aa[u][2]; st.w = aa[u][3];
        *(float4*)(out + O_AFF + (size_t)p * 16 + 4 * q) = st;
        if (q == 0) {
          float* orc = out + O_REC + (size_t)p * 3;
          orc[0] = rc0; orc[1] = rc1; orc[2] = rc2;
          out[O_SPA + p] = err;
        }
      }
    }
    cur = segFirst;
    cntT = NT;
    flush();
    return;
  }

  // ---- SLOW PATH (boundary waves, ~1%): R7's verified code ----
  auto do_pair = [&](int pt0, float (&aa)[2][4], float (&ee)[2], int (&sgv)[2],
                     bool (&vv)[2]) {
    float X[2], Y[2], Z[2];
    bf16x8 Bp[2];
#pragma unroll
    for (int u = 0; u < 2; u++) {
      const int p = pt0 + 16 * u + m;
      vv[u] = (p < N_PTS);
      const int pc = vv[u] ? p : (N_PTS - 1);
      X[u] = pos[pc * 3 + 0];
      Y[u] = pos[pc * 3 + 1];
      Z[u] = pos[pc * 3 + 2];
      sgv[u] = batch[pc];
      bf16x8 b = {0, 0, 0, 0, 0, 0, 0, 0};
      if (q == 0) {
        b[0] = f2bf(X[u]);
        b[1] = f2bf(Y[u]);
        b[2] = f2bf(Z[u]);
        b[3] = one;
      }
      Bp[u] = b;
    }

    bf16x8 Bh[2][4];
#pragma unroll
    for (int u = 0; u < 2; u++)
#pragma unroll
      for (int kb = 0; kb < 4; kb++) {
        f32x4 c0 = __builtin_amdgcn_mfma_f32_16x16x32_bf16(Af1[2 * kb + 0], Bp[u], zf, 0, 0, 0);
        f32x4 c1 = __builtin_amdgcn_mfma_f32_16x16x32_bf16(Af1[2 * kb + 1], Bp[u], zf, 0, 0, 0);
        bf16x8 b;
        b[0] = f2bf(fmaxf(c0[0], 0.f));
        b[1] = f2bf(fmaxf(c0[1], 0.f));
        b[2] = f2bf(fmaxf(c0[2], 0.f));
        b[3] = f2bf(fmaxf(c0[3], 0.f));
        b[4] = f2bf(fmaxf(c1[0], 0.f));
        b[5] = f2bf(fmaxf(c1[1], 0.f));
        b[6] = f2bf(fmaxf(c1[2], 0.f));
        b[7] = f2bf(fmaxf(c1[3], 0.f));
        Bh[u][kb] = b;
      }

    bf16x8 Ba[2];
#pragma unroll
    for (int u = 0; u < 2; u++) {
      f32x4 c01 = __builtin_amdgcn_mfma_f32_16x16x32_bf16(Af2[0], Bh[u][0], zf, 0, 0, 0);
      c01 = __builtin_amdgcn_mfma_f32_16x16x32_bf16(Af2[1], Bh[u][1], c01, 0, 0, 0);
      f32x4 c23 = __builtin_amdgcn_mfma_f32_16x16x32_bf16(Af2[2], Bh[u][2], zf, 0, 0, 0);
      c23 = __builtin_amdgcn_mfma_f32_16x16x32_bf16(Af2[3], Bh[u][3], c23, 0, 0, 0);
      aa[u][0] = c01[0] + c23[0] + bf2r0;
      aa[u][1] = c01[1] + c23[1] + bf2r1;
      aa[u][2] = c01[2] + c23[2] + bf2r2;
      aa[u][3] = c01[3] + c23[3] + bf2r3;
      bf16x8 b;
      b[0] = f2bf(aa[u][0]);
      b[1] = f2bf(aa[u][1]);
      b[2] = f2bf(aa[u][2]);
      b[3] = f2bf(aa[u][3]);
      b[4] = one;
      b[5] = 0;
      b[6] = 0;
      b[7] = 0;
      Ba[u] = b;
    }

    bf16x8 Bh2[2][4];
#pragma unroll
    for (int u = 0; u < 2; u++)
#pragma unroll
      for (int kb = 0; kb < 4; kb++) {
        f32x4 c0 = __builtin_amdgcn_mfma_f32_16x16x32_bf16(Ag1[2 * kb + 0], Ba[u], zf, 0, 0, 0);
        f32x4 c1 = __builtin_amdgcn_mfma_f32_16x16x32_bf16(Ag1[2 * kb + 1], Ba[u], zf, 0, 0, 0);
        bf16x8 b;
        b[0] = f2bf(fmaxf(c0[0], 0.f));
        b[1] = f2bf(fmaxf(c0[1], 0.f));
        b[2] = f2bf(fmaxf(c0[2], 0.f));
        b[3] = f2bf(fmaxf(c0[3], 0.f));
        b[4] = f2bf(fmaxf(c1[0], 0.f));
        b[5] = f2bf(fmaxf(c1[1], 0.f));
        b[6] = f2bf(fmaxf(c1[2], 0.f));
        b[7] = f2bf(fmaxf(c1[3], 0.f));
        Bh2[u][kb] = b;
      }

#pragma unroll
    for (int u = 0; u < 2; u++) {
      f32x4 c01 = __builtin_amdgcn_mfma_f32_16x16x32_bf16(Ag2[0], Bh2[u][0], zf, 0, 0, 0);
      c01 = __builtin_amdgcn_mfma_f32_16x16x32_bf16(Ag2[1], Bh2[u][1], c01, 0, 0, 0);
      f32x4 c23 = __builtin_amdgcn_mfma_f32_16x16x32_bf16(Ag2[2], Bh2[u][2], zf, 0, 0, 0);
      c23 = __builtin_amdgcn_mfma_f32_16x16x32_bf16(Ag2[3], Bh2[u][3], c23, 0, 0, 0);

      float err = 0.f, rc0 = 0.f, rc1 = 0.f, rc2 = 0.f;
      if (q == 0) {
        rc0 = c01[0] + c23[0] + bg20;
        rc1 = c01[1] + c23[1] + bg21;
        rc2 = c01[2] + c23[2] + bg22;
        const float dx = X[u] - rc0, dy = Y[u] - rc1, dz = Z[u] - rc2;
        err = fmaf(dx, dx, fmaf(dy, dy, dz * dz));
      }
      ee[u] = err;

      if (vv[u]) {
        const int p = pt0 + 16 * u + m;
        float4 st;
        st.x = aa[u][0]; st.y = aa[u][1]; st.z = aa[u][2]; st.w = aa[u][3];
        *(float4*)(out + O_AFF + (size_t)p * 16 + 4 * q) = st;
        if (q == 0) {
          float* orc = out + O_REC + (size_t)p * 3;
          orc[0] = rc0; orc[1] = rc1; orc[2] = rc2;
          out[O_SPA + p] = err;
        }
      }
    }
  };

  float aa[2][4];
  float ee[2];
  int sgv[2];
  bool vv[2];
#pragma unroll 1
  for (int tt = 0; tt < NT; tt += 2) {
    do_pair(wbase + tt * 16, aa, ee, sgv, vv);
#pragma unroll
    for (int u = 0; u < 2; u++) {
      const int pt0u = wbase + (tt + u) * 16;
      const int useg = __shfl(sgv[u], 0);
      const bool cln = __all(sgv[u] == useg) && (pt0u + 16 <= N_PTS);
      if (cln && useg == cur) {
        acc0 += aa[u][0]; acc1 += aa[u][1];
        acc2 += aa[u][2]; acc3 += aa[u][3];
        accE += ee[u];
        cntT++;
      } else {
        if (cntT > 0) flush();
        if (cln) {
          cur = useg;
          acc0 = aa[u][0]; acc1 = aa[u][1];
          acc2 = aa[u][2]; acc3 = aa[u][3];
          accE = ee[u];
          cntT = 1;
        } else {
          cur = -1;
          if (vv[u]) {
            float* wp = wsr + sgv[u] * 18;
            atomicAdd(wp + 2 + 4 * q + 0, aa[u][0]);
            atomicAdd(wp + 2 + 4 * q + 1, aa[u][1]);
            atomicAdd(wp + 2 + 4 * q + 2, aa[u][2]);
            atomicAdd(wp + 2 + 4 * q + 3, aa[u][3]);
            if (q == 0) {
              atomicAdd(wp + 0, ee[u]);
              atomicAdd(wp + 1, 1.f);
            }
          }
        }
      }
    }
  }
  if (cntT > 0) flush();
}

// ---------------------------------------------------------------------------
// Kernel 2: one block per segment (64 blocks x 64 threads). Sums ws replicas.
// ---------------------------------------------------------------------------
__global__ __launch_bounds__(64) void agent_kernel(
    const float* __restrict__ ws, int rep, const float* __restrict__ agent_h,
    const float* __restrict__ Wx, const float* __restrict__ Wh,
    const float* __restrict__ bx, const float* __restrict__ bh,
    const float* __restrict__ Wlat, const float* __restrict__ blat,
    const float* __restrict__ Wact, const float* __restrict__ bact,
    float* __restrict__ out) {
  const int b = blockIdx.x;   // segment
  const int t = threadIdx.x;  // 0..63
  __shared__ float sAff[AFFD];
  __shared__ float sHn[AH];
  __shared__ float sLat[AL];

  float errs = 0.f, cnts = 0.f, affs = 0.f;
  for (int r = 0; r < rep; r++) {
    const float* wp = ws + ((size_t)r * B_SEG + b) * 18;
    errs += wp[0];
    cnts += wp[1];
    if (t < AFFD) affs += wp[2 + t];
  }
  const float cnt = fmaxf(cnts, 1.f);
  if (t == 0) out[O_SIG + b] = errs / cnt;
  if (t < AFFD) sAff[t] = affs / cnt;
  const float h_prev = agent_h[b * AH + t];
  __syncthreads();

  float pr  = bx[t] + bh[t];
  float pz  = bx[64 + t] + bh[64 + t];
  float pnx = bx[128 + t];
  float pnh = bh[128 + t];
#pragma unroll
  for (int k = 0; k < AFFD; k++) {
    const float a = sAff[k];
    pr  = fmaf(a, Wx[k * 192 + t], pr);
    pz  = fmaf(a, Wx[k * 192 + 64 + t], pz);
    pnx = fmaf(a, Wx[k * 192 + 128 + t], pnx);
  }
#pragma unroll
  for (int k = 0; k < AH; k++) {
    const float h = __shfl(h_prev, k);
    pr  = fmaf(h, Wh[k * 192 + t], pr);
    pz  = fmaf(h, Wh[k * 192 + 64 + t], pz);
    pnh = fmaf(h, Wh[k * 192 + 128 + t], pnh);
  }
  const float r = 1.f / (1.f + expf(-pr));
  const float z = 1.f / (1.f + expf(-pz));
  const float n = tanhf(pnx + r * pnh);
  const float hn = fmaf(1.f - z, n, z * h_prev);
  sHn[t] = hn;
  out[O_HN + b * AH + t] = hn;
  __syncthreads();

  if (t < AL) {
    float acc = blat[t];
#pragma unroll
    for (int k = 0; k < AH; k++) acc = fmaf(sHn[k], Wlat[k * AL + t], acc);
    sLat[t] = tanhf(acc);
  }
  __syncthreads();

  if (t < AA) {
    float acc = bact[t];
#pragma unroll
    for (int k = 0; k < AL; k++) acc = fmaf(sLat[k], Wact[k * AA + t], acc);
    out[O_ACT + b * AA + t] = acc;
  }
}

extern "C" void kernel_launch(void* const* d_in, const int* in_sizes, int n_in,
                              void* d_out, int out_size, void* d_ws, size_t ws_size,
                              hipStream_t stream) {
  const float* pos     = (const float*)d_in[0];
  const int*   batch   = (const int*)d_in[1];
  const float* agent_h = (const float*)d_in[2];
  // d_in[3], d_in[4]: coherence_*_prev — unused by the math.
  const float* Wf1  = (const float*)d_in[5];
  const float* bf1v = (const float*)d_in[6];
  const float* Wf2  = (const float*)d_in[7];
  const float* bf2v = (const float*)d_in[8];
  const float* Wg1  = (const float*)d_in[9];
  const float* bg1v = (const float*)d_in[10];
  const float* Wg2  = (const float*)d_in[11];
  const float* bg2v = (const float*)d_in[12];
  const float* Wx   = (const float*)d_in[13];
  const float* Wh   = (const float*)d_in[14];
  const float* bx   = (const float*)d_in[15];
  const float* bh   = (const float*)d_in[16];
  const float* Wlat = (const float*)d_in[17];
  const float* blat = (const float*)d_in[18];
  const float* Wact = (const float*)d_in[19];
  const float* bact = (const float*)d_in[20];
  float* out = (float*)d_out;
  float* ws = (float*)d_ws;

  // ws replicas (atomic de-contention), bounded by the provided workspace.
  const size_t one_rep = (size_t)B_SEG * 18 * sizeof(float);
  int rep = (int)(ws_size / one_rep);
  if (rep > MAX_REP) rep = MAX_REP;
  if (rep < 1) rep = 1;

  // ws is re-poisoned 0xAA before every launch — zero the accumulators.
  hipMemsetAsync(ws, 0, (size_t)rep * one_rep, stream);

  const int nblk = (N_PTS + PTS_BLK - 1) / PTS_BLK;  // 1954
  point_kernel<<<nblk, TPB, 0, stream>>>(pos, batch, Wf1, bf1v, Wf2, bf2v,
                                         Wg1, bg1v, Wg2, bg2v, out, ws, rep);
  agent_kernel<<<B_SEG, 64, 0, stream>>>(ws, rep, agent_h, Wx, Wh, bx, bh,
                                         Wlat, blat, Wact, bact, out);
}